// Round 7
// baseline (507.713 us; speedup 1.0000x reference)
//
#include <hip/hip_runtime.h>
#include <cstdint>
#include <cstddef>

// PatchAttention on MI355X — round 9:
//  - embed GEMM: back to the LDS/global_load_lds structure (round 7) but
//    split-K x8 -> grid 1024 = 4 blocks/CU. Round-8 post-mortem: reg-staged
//    "pipeline" was defeated by regalloc (VGPR=104 => loads sunk to use);
//    2 blocks/CU gave no TLP. m97/m114 evidence: same structure at >=3
//    blocks/CU gets implicit cross-block overlap.
//  - splitk_reduce templated on split count (8 for embed, 4 for proj).
//  - attention + other GEMMs unchanged from round 8.

typedef __bf16 bf16x8 __attribute__((ext_vector_type(8)));
typedef float f32x4 __attribute__((ext_vector_type(4)));
typedef unsigned short u16x4 __attribute__((ext_vector_type(4)));

__device__ __forceinline__ unsigned short f2bf(float f) {
  unsigned u = __builtin_bit_cast(unsigned, f);
  u += 0x7fffu + ((u >> 16) & 1u);  // round-to-nearest-even
  return (unsigned short)(u >> 16);
}
__device__ __forceinline__ float bf2f(unsigned short u) {
  return __builtin_bit_cast(float, ((unsigned)u) << 16);
}

// async 16B global -> LDS (wave-uniform base + lane*16 layout)
__device__ __forceinline__ void async_ld16(const void* g, void* l) {
  __builtin_amdgcn_global_load_lds(
      (const __attribute__((address_space(1))) void*)g,
      (__attribute__((address_space(3))) void*)l, 16, 0, 0);
}

__device__ __forceinline__ void cvt8_store(unsigned short* dst, float4 a,
                                           float4 b) {
  unsigned short t[8] = {f2bf(a.x), f2bf(a.y), f2bf(a.z), f2bf(a.w),
                         f2bf(b.x), f2bf(b.y), f2bf(b.z), f2bf(b.w)};
  *(uint4*)dst = *(const uint4*)t;
}

// ---------------------------------------------------------------------------
// RPE table: MLP(2 -> 512 -> 8) over the 63x63 grid -> tableT [8][4096] f32.
__global__ __launch_bounds__(256) void rpe_table_kernel(
    const float* __restrict__ w1, const float* __restrict__ b1,
    const float* __restrict__ w2, float* __restrict__ tableT) {
  int t = blockIdx.x * 256 + threadIdx.x;
  if (t >= 3969) return;
  int a = t / 63, c = t - a * 63;
  float rh = (float)(a - 31) * (1.0f / 31.0f);
  float rw = (float)(c - 31) * (1.0f / 31.0f);
  float acc[8];
#pragma unroll
  for (int h = 0; h < 8; h++) acc[h] = 0.f;
  for (int j = 0; j < 512; j++) {
    float hv = fmaxf(rh * w1[2 * j] + rw * w1[2 * j + 1] + b1[j], 0.f);
#pragma unroll
    for (int h = 0; h < 8; h++) acc[h] += hv * w2[h * 512 + j];
  }
#pragma unroll
  for (int h = 0; h < 8; h++) tableT[h * 4096 + t] = acc[h];
}

// ---------------------------------------------------------------------------
// generic fp32 -> bf16 convert, 8 elems/thread
__global__ __launch_bounds__(256) void cvt_bf16_kernel(
    const float* __restrict__ src, unsigned short* __restrict__ dst, int n8) {
  int i = blockIdx.x * 256 + threadIdx.x;
  if (i >= n8) return;
  const float4* s4 = (const float4*)src + (size_t)i * 2;
  float4 a = s4[0], b = s4[1];
  unsigned short t[8] = {f2bf(a.x), f2bf(a.y), f2bf(a.z), f2bf(a.w),
                         f2bf(b.x), f2bf(b.y), f2bf(b.z), f2bf(b.w)};
  *(uint4*)(dst + (size_t)i * 8) = *(const uint4*)t;
}

// transpose+convert: src [256][4096] f32 -> dst [4096][256] bf16
__global__ __launch_bounds__(256) void transpose_cvt_kernel(
    const float* __restrict__ src, unsigned short* __restrict__ dst) {
  __shared__ float tile[32][33];
  int bx = blockIdx.x;
  int by = blockIdx.y;
  int tx = threadIdx.x & 31, ty = threadIdx.x >> 5;
#pragma unroll
  for (int r = 0; r < 32; r += 8)
    tile[ty + r][tx] = src[(size_t)(by * 32 + ty + r) * 4096 + bx * 32 + tx];
  __syncthreads();
#pragma unroll
  for (int r = 0; r < 32; r += 8)
    dst[(size_t)(bx * 32 + ty + r) * 256 + by * 32 + tx] = f2bf(tile[tx][ty + r]);
}

// ---------------------------------------------------------------------------
// splitk reduce: out[8192*256] bf16 = sum_{s<NS} part[s][.] + bias[col]
template <int NS>
__global__ __launch_bounds__(256) void splitk_reduce_kernel(
    const float* __restrict__ part, const float* __restrict__ bias,
    unsigned short* __restrict__ out) {
  size_t i = ((size_t)blockIdx.x * 256 + threadIdx.x) * 8;
  const float4* p = (const float4*)(part + i);
  const size_t s4 = 2097152 / 4;  // float4 stride per split
  float4 a0 = p[0], a1 = p[1];
#pragma unroll
  for (int s = 1; s < NS; s++) {
    float4 b0 = p[s * s4], b1 = p[s * s4 + 1];
    a0.x += b0.x; a0.y += b0.y; a0.z += b0.z; a0.w += b0.w;
    a1.x += b1.x; a1.y += b1.y; a1.z += b1.z; a1.w += b1.w;
  }
  int col = (int)(i & 255);
  unsigned short t8[8] = {
      f2bf(a0.x + bias[col + 0]), f2bf(a0.y + bias[col + 1]),
      f2bf(a0.z + bias[col + 2]), f2bf(a0.w + bias[col + 3]),
      f2bf(a1.x + bias[col + 4]), f2bf(a1.y + bias[col + 5]),
      f2bf(a1.z + bias[col + 6]), f2bf(a1.w + bias[col + 7])};
  *(uint4*)(out + i) = *(const uint4*)t8;
}

// ---------------------------------------------------------------------------
// Embed GEMM, fused im2col, LDS-staged, split-K x8:
//   Cpart[z][8192][256] f32 = x-as-A[8192, z*512 .. +512] * wE^T
// A staged reg->LDS (f32 loads + cvt), B staged via global_load_lds.
// Grid: 1024 linear blocks (4 blocks/CU); XCD-pairing swizzle keeps both
// n-tiles of one (y,z) panel on one XCD.
__global__ __launch_bounds__(256) void gemm_embed_kernel(
    const float* __restrict__ x, const unsigned short* __restrict__ Bw,
    float* __restrict__ Cpart) {
  __shared__ unsigned short As[2 * 128 * 32];
  __shared__ unsigned short Bs[2 * 128 * 32];
  int tid = threadIdx.x;
  int lane = tid & 63, wave = tid >> 6;

  int L = blockIdx.x;               // 0..1023
  int xcd = L & 7, j = L >> 3;      // j 0..127
  int pair = xcd * 64 + (j >> 1);   // 0..511 (bijective)
  int n0 = (j & 1) * 128;
  int z = pair & 7, y = pair >> 3;  // z 0..7, y 0..63
  int m0 = y * 128;
  int wm = (wave & 1) * 64, wn = (wave >> 1) * 64;
  int fr = lane & 15, fh = lane >> 4;

  f32x4 acc[4][4];
#pragma unroll
  for (int i = 0; i < 4; i++)
#pragma unroll
    for (int jj = 0; jj < 4; jj++) acc[i][jj] = (f32x4){0.f, 0.f, 0.f, 0.f};

  int f0 = tid, f1 = tid + 256;
  // B staging (bf16 weights [256][4096]) via global_load_lds
  const unsigned short* Bg0 =
      Bw + (size_t)(n0 + (f0 >> 2)) * 4096 + z * 512 + (f0 & 3) * 8;
  const unsigned short* Bg1 =
      Bw + (size_t)(n0 + (f1 >> 2)) * 4096 + z * 512 + (f1 & 3) * 8;
  unsigned short* Bl0 = Bs + f0 * 8;
  unsigned short* Bl1 = Bs + f1 * 8;

  // A staging from x: chunk f -> row r=f>>2, ch=f&3;
  // k = z*512 + t*32 + ch*8 -> c = z*32 + (ch>>1), p0 = (2ch)&3
  const float4* x4 = (const float4*)x;
  int r0 = f0 >> 2, ch0 = f0 & 3;
  int m_0 = m0 + r0, b_0 = m_0 >> 10, hp0 = (m_0 >> 5) & 31, wp0 = m_0 & 31;
  int c_0 = z * 32 + (ch0 >> 1), p_0 = (2 * ch0) & 3;
  const float4* xp0 =
      x4 + (size_t)((b_0 * 256 + c_0) * 128 + hp0 * 4 + p_0) * 32 + wp0;
  int r1 = f1 >> 2, ch1 = f1 & 3;
  int m_1 = m0 + r1, b_1 = m_1 >> 10, hp1 = (m_1 >> 5) & 31, wp1 = m_1 & 31;
  int c_1 = z * 32 + (ch1 >> 1), p_1 = (2 * ch1) & 3;
  const float4* xp1 =
      x4 + (size_t)((b_1 * 256 + c_1) * 128 + hp1 * 4 + p_1) * 32 + wp1;
  unsigned short* Al0 = As + f0 * 8;
  unsigned short* Al1 = As + f1 * 8;

  // prologue: tile 0
  float4 a00 = xp0[0], a01 = xp0[32], a10 = xp1[0], a11 = xp1[32];
  xp0 += 8192; xp1 += 8192;  // +32 k = +2 channels
  async_ld16(Bg0, Bl0);
  async_ld16(Bg1, Bl1);
  cvt8_store(Al0, a00, a01);
  cvt8_store(Al1, a10, a11);
  __syncthreads();

  for (int t = 0; t < 16; t++) {
    int cur = (t & 1) << 12, nxt = cur ^ 4096;
    if (t < 15) {  // issue next-tile loads (A consumed after MFMA block)
      a00 = xp0[0]; a01 = xp0[32]; a10 = xp1[0]; a11 = xp1[32];
      xp0 += 8192; xp1 += 8192;
      int kn = (t + 1) << 5;
      async_ld16(Bg0 + kn, Bl0 + nxt);
      async_ld16(Bg1 + kn, Bl1 + nxt);
    }
    const unsigned short* Asc = As + cur;
    const unsigned short* Bsc = Bs + cur;
    bf16x8 af[4], bfr[4];
#pragma unroll
    for (int tt = 0; tt < 4; tt++) {
      af[tt] = *(const bf16x8*)(Asc + (wm + tt * 16 + fr) * 32 + fh * 8);
      bfr[tt] = *(const bf16x8*)(Bsc + (wn + tt * 16 + fr) * 32 + fh * 8);
    }
#pragma unroll
    for (int mt = 0; mt < 4; mt++)
#pragma unroll
      for (int nt = 0; nt < 4; nt++)
        acc[mt][nt] = __builtin_amdgcn_mfma_f32_16x16x32_bf16(
            af[mt], bfr[nt], acc[mt][nt], 0, 0, 0);
    if (t < 15) {
      cvt8_store(Al0 + nxt, a00, a01);
      cvt8_store(Al1 + nxt, a10, a11);
    }
    __syncthreads();
  }

  // epilogue: f32 partials (C/D layout col = lane&15, row = (lane>>4)*4 + r)
  float* Cp = Cpart + (size_t)z * 2097152;
#pragma unroll
  for (int mt = 0; mt < 4; mt++) {
    int row0 = m0 + wm + mt * 16 + fh * 4;
#pragma unroll
    for (int nt = 0; nt < 4; nt++) {
      int col = n0 + wn + nt * 16 + fr;
#pragma unroll
      for (int r = 0; r < 4; r++)
        Cp[(size_t)(row0 + r) * 256 + col] = acc[mt][nt][r];
    }
  }
}

// ---------------------------------------------------------------------------
// bf16 MFMA GEMM: C[M,N] = A[M,K] * B^T (B given [N,K] bf16) + bias.
// CMODE: 1 = bf16 C, 2 = fused col2im into y[8,256,128,128] f32,
//        3 = fused QKV split, 4 = split-K f32 partials.
template <int CMODE>
__global__ __launch_bounds__(256) void gemm_mfma_kernel(
    const unsigned short* __restrict__ A, const unsigned short* __restrict__ B,
    const float* __restrict__ bias, void* __restrict__ Cv,
    int M, int N, int K, int lda, int ldb, int ldc) {
  __shared__ unsigned short As[2 * 128 * 32];
  __shared__ unsigned short Bs[2 * 128 * 32];
  int tid = threadIdx.x;
  int lane = tid & 63;
  int wave = tid >> 6;
  int m0 = blockIdx.y * 128, n0 = blockIdx.x * 128;
  int wm = (wave & 1) * 64, wn = (wave >> 1) * 64;

  if (CMODE == 4) {
    int s = blockIdx.z;
    A += (size_t)s * K;
    B += (size_t)s * K;
    Cv = (void*)((float*)Cv + (size_t)s * M * N);
  }

  f32x4 acc[4][4];
#pragma unroll
  for (int i = 0; i < 4; i++)
#pragma unroll
    for (int j = 0; j < 4; j++) acc[i][j] = (f32x4){0.f, 0.f, 0.f, 0.f};

  int f0 = tid, f1 = tid + 256;
  const unsigned short* Ag0 = A + (size_t)(m0 + (f0 >> 2)) * lda + (f0 & 3) * 8;
  const unsigned short* Ag1 = A + (size_t)(m0 + (f1 >> 2)) * lda + (f1 & 3) * 8;
  const unsigned short* Bg0 = B + (size_t)(n0 + (f0 >> 2)) * ldb + (f0 & 3) * 8;
  const unsigned short* Bg1 = B + (size_t)(n0 + (f1 >> 2)) * ldb + (f1 & 3) * 8;
  unsigned short* Al0 = As + f0 * 8;
  unsigned short* Al1 = As + f1 * 8;
  unsigned short* Bl0 = Bs + f0 * 8;
  unsigned short* Bl1 = Bs + f1 * 8;

  int fr = lane & 15;
  int fh = lane >> 4;

  int ntiles = K >> 5;
  async_ld16(Ag0, Al0);
  async_ld16(Ag1, Al1);
  async_ld16(Bg0, Bl0);
  async_ld16(Bg1, Bl1);
  __syncthreads();

  for (int t = 0; t < ntiles; t++) {
    int cur = (t & 1) << 12;
    int nxt = cur ^ 4096;
    if (t + 1 < ntiles) {
      int kn = (t + 1) << 5;
      async_ld16(Ag0 + kn, Al0 + nxt);
      async_ld16(Ag1 + kn, Al1 + nxt);
      async_ld16(Bg0 + kn, Bl0 + nxt);
      async_ld16(Bg1 + kn, Bl1 + nxt);
    }
    const unsigned short* Asc = As + cur;
    const unsigned short* Bsc = Bs + cur;
    bf16x8 af[4], bfr[4];
#pragma unroll
    for (int tt = 0; tt < 4; tt++) {
      af[tt] = *(const bf16x8*)(Asc + (wm + tt * 16 + fr) * 32 + fh * 8);
      bfr[tt] = *(const bf16x8*)(Bsc + (wn + tt * 16 + fr) * 32 + fh * 8);
    }
#pragma unroll
    for (int mt = 0; mt < 4; mt++)
#pragma unroll
      for (int nt = 0; nt < 4; nt++)
        acc[mt][nt] = __builtin_amdgcn_mfma_f32_16x16x32_bf16(
            af[mt], bfr[nt], acc[mt][nt], 0, 0, 0);
    __syncthreads();
  }

#pragma unroll
  for (int mt = 0; mt < 4; mt++) {
    int row0 = m0 + wm + mt * 16 + fh * 4;
    if (CMODE == 2) {
      int b = row0 >> 10, hp = (row0 >> 5) & 31, wp = row0 & 31;
      size_t rowoff0 = (size_t)b * 4194304 + hp * 512 + wp * 4;
      float* y = (float*)Cv;
#pragma unroll
      for (int nt = 0; nt < 4; nt++) {
        int col = n0 + wn + nt * 16 + fr;
        int o = col >> 4, p = (col >> 2) & 3, q = col & 3;
        size_t coloff = (size_t)o * 16384 + p * 128 + q;
        float bv = bias[o];
#pragma unroll
        for (int r = 0; r < 4; r++)
          y[rowoff0 + r * 4 + coloff] = acc[mt][nt][r] + bv;
      }
    } else if (CMODE == 3) {
      unsigned short* base = (unsigned short*)Cv;
#pragma unroll
      for (int nt = 0; nt < 4; nt++) {
        int col = n0 + wn + nt * 16 + fr;
        int which = col >> 8, hh = (col >> 5) & 7, d = col & 31;
        float bv = bias[col];
#pragma unroll
        for (int r = 0; r < 4; r++) {
          int row = row0 + r;
          int bb = row >> 10, nn = row & 1023;
          int bh = bb * 8 + hh;
          float v = acc[mt][nt][r] + bv;
          if (which == 0) v *= 0.17677669529663687f;  // 1/sqrt(32)
          size_t addr;
          if (which < 2)
            addr = (size_t)which * 2097152 + ((size_t)bh * 1024 + nn) * 32 + d;
          else
            addr = (size_t)2 * 2097152 + (size_t)bh * 32768 + (size_t)d * 1024 + nn;
          base[addr] = f2bf(v);
        }
      }
    } else if (CMODE == 4) {
      float* Cp = (float*)Cv;
#pragma unroll
      for (int nt = 0; nt < 4; nt++) {
        int col = n0 + wn + nt * 16 + fr;
#pragma unroll
        for (int r = 0; r < 4; r++)
          Cp[(size_t)(row0 + r) * ldc + col] = acc[mt][nt][r];
      }
    } else {
#pragma unroll
      for (int nt = 0; nt < 4; nt++) {
        int col = n0 + wn + nt * 16 + fr;
        float bv = bias ? bias[col] : 0.f;
        unsigned short* C = (unsigned short*)Cv;
#pragma unroll
        for (int r = 0; r < 4; r++)
          C[(size_t)(row0 + r) * ldc + col] = f2bf(acc[mt][nt][r] + bv);
      }
    }
  }
}

// ---------------------------------------------------------------------------
// MFMA flash attention — barrier-free, rolled 8x2 pipelined loop (round 7).
__global__ __launch_bounds__(512) void attn_mfma_kernel(
    const unsigned short* __restrict__ Qb, const unsigned short* __restrict__ Kb,
    const unsigned short* __restrict__ Vtb,
    const float* __restrict__ tableT,
    unsigned short* __restrict__ out) {
  __shared__ float th[3972];                 // per-head RPE table column
  __shared__ unsigned short Ps[2][8][1088];  // [half][wave][16*68] P scratch

  int tid = threadIdx.x;
  int lane = tid & 63, w = tid >> 6;
  int n = lane & 15, g = lane >> 4;
  int blk = blockIdx.x;
  int h = blk & 7, b = (blk >> 3) & 7, qt = blk >> 6;
  int bh = b * 8 + h;
  int q0 = qt * 128;

  const unsigned short* Qg = Qb + ((size_t)bh * 1024 + q0) * 32;
  const unsigned short* Kg = Kb + (size_t)bh * 1024 * 32;
  const unsigned short* Vg = Vtb + (size_t)bh * 32 * 1024;
  const float* tg = tableT + (size_t)h * 4096;

  for (int i = tid; i < 3969; i += 512) th[i] = tg[i];
  bf16x8 qf = *(const bf16x8*)(Qg + (size_t)(w * 16 + n) * 32 + g * 8);
  __syncthreads();  // table ready — the only barrier

  f32x4 oacc[2];
  oacc[0] = (f32x4){0.f, 0.f, 0.f, 0.f};
  oacc[1] = (f32x4){0.f, 0.f, 0.f, 0.f};
  float m_run = -1e30f, l_run = 0.f;  // l_run g-partial, reduced at end

  int q = q0 + w * 16 + n;
  int tbase = (q >> 5) * 63 + (q & 31) + 1984;  // + (31*63+31)

  unsigned short* PwA = &Ps[0][w][0];
  unsigned short* PwB = &Ps[1][w][0];

  bf16x8 kfA[4], kfB[4];
#pragma unroll
  for (int mt = 0; mt < 4; mt++)
    kfA[mt] = *(const bf16x8*)(Kg + (size_t)(mt * 16 + n) * 32 + g * 8);

  auto half_step = [&](const bf16x8 (&kf)[4], int k0, unsigned short* Pw) {
    bf16x8 vf[4];
#pragma unroll
    for (int i = 0; i < 4; i++)
      vf[i] = *(const bf16x8*)(Vg + (size_t)((i & 1) * 16 + n) * 1024 + k0 +
                               (i >> 1) * 32 + g * 8);

    f32x4 s[4];
    __builtin_amdgcn_s_setprio(1);
#pragma unroll
    for (int mt = 0; mt < 4; mt++)
      s[mt] = __builtin_amdgcn_mfma_f32_16x16x32_bf16(
          kf[mt], qf, (f32x4){0.f, 0.f, 0.f, 0.f}, 0, 0, 0);
    __builtin_amdgcn_s_setprio(0);

#pragma unroll
    for (int mt = 0; mt < 4; mt++) {
      int kb = k0 + mt * 16 + g * 4;
      int ib = tbase - (kb >> 5) * 63 - (kb & 31);
      s[mt][0] += th[ib];
      s[mt][1] += th[ib - 1];
      s[mt][2] += th[ib - 2];
      s[mt][3] += th[ib - 3];
    }

    float mx = -1e30f;
#pragma unroll
    for (int mt = 0; mt < 4; mt++)
#pragma unroll
      for (int r = 0; r < 4; r++) mx = fmaxf(mx, s[mt][r]);
    mx = fmaxf(mx, __shfl_xor(mx, 16, 64));
    mx = fmaxf(mx, __shfl_xor(mx, 32, 64));
    float m_new = fmaxf(m_run, mx);
    float alpha = __expf(m_run - m_new);
    m_run = m_new;

    float ls = 0.f;
#pragma unroll
    for (int mt = 0; mt < 4; mt++) {
#pragma unroll
      for (int r = 0; r < 4; r++) {
        float p = __expf(s[mt][r] - m_new);
        s[mt][r] = p;
        ls += p;
      }
      u16x4 pk = {f2bf(s[mt][0]), f2bf(s[mt][1]), f2bf(s[mt][2]),
                  f2bf(s[mt][3])};
      *(u16x4*)(Pw + n * 68 + mt * 16 + g * 4) = pk;
    }
    l_run = l_run * alpha + ls;

#pragma unroll
    for (int dt = 0; dt < 2; dt++)
#pragma unroll
      for (int r = 0; r < 4; r++) oacc[dt][r] *= alpha;
    __builtin_amdgcn_s_setprio(1);
#pragma unroll
    for (int kt = 0; kt < 2; kt++) {
      bf16x8 pf = *(const bf16x8*)(Pw + n * 68 + kt * 32 + g * 8);
      oacc[0] = __builtin_amdgcn_mfma_f32_16x16x32_bf16(vf[kt * 2 + 0], pf,
                                                        oacc[0], 0, 0, 0);
      oacc[1] = __builtin_amdgcn_mfma_f32_16x16x32_bf16(vf[kt * 2 + 1], pf,
                                                        oacc[1], 0, 0, 0);
    }
    __builtin_amdgcn_s_setprio(0);
  };

  for (int tt = 0; tt < 8; tt++) {
    int k0 = tt * 128;
#pragma unroll
    for (int mt = 0; mt < 4; mt++)
      kfB[mt] = *(const bf16x8*)(Kg + (size_t)(k0 + 64 + mt * 16 + n) * 32 +
                                 g * 8);
    half_step(kfA, k0, PwA);
    if (tt < 7) {
#pragma unroll
      for (int mt = 0; mt < 4; mt++)
        kfA[mt] = *(const bf16x8*)(Kg + (size_t)(k0 + 128 + mt * 16 + n) * 32 +
                                   g * 8);
    }
    half_step(kfB, k0 + 64, PwB);
  }

  float l = l_run;
  l += __shfl_xor(l, 16, 64);
  l += __shfl_xor(l, 32, 64);
  float invl = 1.f / l;
  unsigned short* ob = out + ((size_t)(b * 1024 + q) * 256) + h * 32;
#pragma unroll
  for (int dt = 0; dt < 2; dt++) {
    u16x4 o4 = {f2bf(oacc[dt][0] * invl), f2bf(oacc[dt][1] * invl),
                f2bf(oacc[dt][2] * invl), f2bf(oacc[dt][3] * invl)};
    *(u16x4*)(ob + dt * 16 + g * 4) = o4;
  }
}

// ---------------------------------------------------------------------------
extern "C" void kernel_launch(void* const* d_in, const int* in_sizes, int n_in,
                              void* d_out, int out_size, void* d_ws, size_t ws_size,
                              hipStream_t stream) {
  const float* x         = (const float*)d_in[0];
  const float* w_embed   = (const float*)d_in[1];
  const float* b_embed   = (const float*)d_in[2];
  const float* cpb_w1    = (const float*)d_in[3];
  const float* cpb_b1    = (const float*)d_in[4];
  const float* cpb_w2    = (const float*)d_in[5];
  const float* w_qkv     = (const float*)d_in[6];
  const float* b_qkv     = (const float*)d_in[7];
  const float* w_proj    = (const float*)d_in[8];
  const float* b_proj    = (const float*)d_in[9];
  const float* w_unembed = (const float*)d_in[10];
  const float* b_unembed = (const float*)d_in[11];
  float* out = (float*)d_out;

  // workspace layout (~104.6 MB; matches the 104.6 MB round-3 layout that ran)
  char* w = (char*)d_ws;
  float*          ProjP = (float*)w;          w += (size_t)8388608 * 4;      // 32 MB (proj partials)
  unsigned short* tok   = (unsigned short*)w; w += (size_t)8192 * 256 * 2;   //  4 MB
  unsigned short* wE    = (unsigned short*)w; w += (size_t)1048576 * 2;      //  2 MB
  unsigned short* wQ    = (unsigned short*)w; w += (size_t)196608 * 2;       // 384 KB
  unsigned short* wP    = (unsigned short*)w; w += (size_t)65536 * 2;        // 128 KB
  unsigned short* wUt   = (unsigned short*)w; w += (size_t)1048576 * 2;      //  2 MB
  float*          tableT= (float*)w;          w += (size_t)32768 * 4;        // 128 KB
  float*          PART  = (float*)w;          w += (size_t)8 * 2097152 * 4;  // 64 MB (embed partials x8)

  // live-range aliases inside PART (embed partials dead once reduced):
  unsigned short* qkvB  = (unsigned short*)PART;                     // 12 MB
  unsigned short* attno = (unsigned short*)((char*)PART + 12582912); //  4 MB
  unsigned short* z2    = (unsigned short*)((char*)PART + 16777216); //  4 MB
  unsigned short* Qb  = qkvB;
  unsigned short* Kb  = qkvB + 2097152;
  unsigned short* Vtb = qkvB + 2 * 2097152;

  // ---- prep (weights, RPE table) ----
  cvt_bf16_kernel<<<512, 256, 0, stream>>>(w_embed, wE, 131072);
  cvt_bf16_kernel<<<96, 256, 0, stream>>>(w_qkv, wQ, 24576);
  cvt_bf16_kernel<<<32, 256, 0, stream>>>(w_proj, wP, 8192);
  transpose_cvt_kernel<<<dim3(128, 8), 256, 0, stream>>>(w_unembed, wUt);
  rpe_table_kernel<<<16, 256, 0, stream>>>(cpb_w1, cpb_b1, cpb_w2, tableT);

  // ---- embed: fused-im2col split-K x8 (4 blocks/CU) -> reduce -> tok ----
  gemm_embed_kernel<<<1024, 256, 0, stream>>>(x, wE, PART);
  splitk_reduce_kernel<8><<<1024, 256, 0, stream>>>(PART, b_embed, tok);

  // ---- qkv + fused split/scale/transpose into Qb/Kb/Vtb ----
  gemm_mfma_kernel<3><<<dim3(6, 64), 256, 0, stream>>>(
      tok, wQ, b_qkv, qkvB, 8192, 768, 256, 256, 256, 0);

  // ---- attention (barrier-free, rolled 8x2) ----
  attn_mfma_kernel<<<512, 512, 0, stream>>>(Qb, Kb, Vtb, tableT, attno);

  // ---- proj: split-K x4 -> reduce -> z2 ----
  gemm_mfma_kernel<4><<<dim3(2, 64, 4), 256, 0, stream>>>(
      attno, wP, nullptr, ProjP, 8192, 256, 64, 256, 256, 256);
  splitk_reduce_kernel<4><<<1024, 256, 0, stream>>>(ProjP, b_proj, z2);

  // ---- unembed + fused col2im ----
  gemm_mfma_kernel<2><<<dim3(32, 64), 256, 0, stream>>>(
      z2, wUt, b_unembed, out, 8192, 4096, 256, 256, 256, 0);
}

// Round 8
// 483.163 us; speedup vs baseline: 1.0508x; 1.0508x over previous
//
#include <hip/hip_runtime.h>
#include <cstdint>
#include <cstddef>

// PatchAttention on MI355X — round 10:
//  - embed GEMM: counted-vmcnt raw-barrier k-loop (T4). A (f32 x) reg-staged
//    2 tiles deep (named aP/aQ sets); B quad-buffered LDS ring via
//    global_load_lds; per-step barrier = asm "s_waitcnt vmcnt(6) lgkmcnt(0);
//    s_barrier" so prefetch loads stay in flight ACROSS barriers (never
//    drain to 0 in the loop — the m97-structure stall all prior variants hit).
//  - split-K back to x4 (x8 only added 33 MB partial traffic).
//  - attention + other GEMMs unchanged.

typedef __bf16 bf16x8 __attribute__((ext_vector_type(8)));
typedef float f32x4 __attribute__((ext_vector_type(4)));
typedef unsigned short u16x4 __attribute__((ext_vector_type(4)));

__device__ __forceinline__ unsigned short f2bf(float f) {
  unsigned u = __builtin_bit_cast(unsigned, f);
  u += 0x7fffu + ((u >> 16) & 1u);  // round-to-nearest-even
  return (unsigned short)(u >> 16);
}
__device__ __forceinline__ float bf2f(unsigned short u) {
  return __builtin_bit_cast(float, ((unsigned)u) << 16);
}

// async 16B global -> LDS (wave-uniform base + lane*16 layout)
__device__ __forceinline__ void async_ld16(const void* g, void* l) {
  __builtin_amdgcn_global_load_lds(
      (const __attribute__((address_space(1))) void*)g,
      (__attribute__((address_space(3))) void*)l, 16, 0, 0);
}

__device__ __forceinline__ void cvt8_store(unsigned short* dst, float4 a,
                                           float4 b) {
  unsigned short t[8] = {f2bf(a.x), f2bf(a.y), f2bf(a.z), f2bf(a.w),
                         f2bf(b.x), f2bf(b.y), f2bf(b.z), f2bf(b.w)};
  *(uint4*)dst = *(const uint4*)t;
}

// ---------------------------------------------------------------------------
// RPE table: MLP(2 -> 512 -> 8) over the 63x63 grid -> tableT [8][4096] f32.
__global__ __launch_bounds__(256) void rpe_table_kernel(
    const float* __restrict__ w1, const float* __restrict__ b1,
    const float* __restrict__ w2, float* __restrict__ tableT) {
  int t = blockIdx.x * 256 + threadIdx.x;
  if (t >= 3969) return;
  int a = t / 63, c = t - a * 63;
  float rh = (float)(a - 31) * (1.0f / 31.0f);
  float rw = (float)(c - 31) * (1.0f / 31.0f);
  float acc[8];
#pragma unroll
  for (int h = 0; h < 8; h++) acc[h] = 0.f;
  for (int j = 0; j < 512; j++) {
    float hv = fmaxf(rh * w1[2 * j] + rw * w1[2 * j + 1] + b1[j], 0.f);
#pragma unroll
    for (int h = 0; h < 8; h++) acc[h] += hv * w2[h * 512 + j];
  }
#pragma unroll
  for (int h = 0; h < 8; h++) tableT[h * 4096 + t] = acc[h];
}

// ---------------------------------------------------------------------------
// generic fp32 -> bf16 convert, 8 elems/thread
__global__ __launch_bounds__(256) void cvt_bf16_kernel(
    const float* __restrict__ src, unsigned short* __restrict__ dst, int n8) {
  int i = blockIdx.x * 256 + threadIdx.x;
  if (i >= n8) return;
  const float4* s4 = (const float4*)src + (size_t)i * 2;
  float4 a = s4[0], b = s4[1];
  unsigned short t[8] = {f2bf(a.x), f2bf(a.y), f2bf(a.z), f2bf(a.w),
                         f2bf(b.x), f2bf(b.y), f2bf(b.z), f2bf(b.w)};
  *(uint4*)(dst + (size_t)i * 8) = *(const uint4*)t;
}

// transpose+convert: src [256][4096] f32 -> dst [4096][256] bf16
__global__ __launch_bounds__(256) void transpose_cvt_kernel(
    const float* __restrict__ src, unsigned short* __restrict__ dst) {
  __shared__ float tile[32][33];
  int bx = blockIdx.x;
  int by = blockIdx.y;
  int tx = threadIdx.x & 31, ty = threadIdx.x >> 5;
#pragma unroll
  for (int r = 0; r < 32; r += 8)
    tile[ty + r][tx] = src[(size_t)(by * 32 + ty + r) * 4096 + bx * 32 + tx];
  __syncthreads();
#pragma unroll
  for (int r = 0; r < 32; r += 8)
    dst[(size_t)(bx * 32 + ty + r) * 256 + by * 32 + tx] = f2bf(tile[tx][ty + r]);
}

// ---------------------------------------------------------------------------
// splitk reduce: out[8192*256] bf16 = sum_{s<NS} part[s][.] + bias[col]
template <int NS>
__global__ __launch_bounds__(256) void splitk_reduce_kernel(
    const float* __restrict__ part, const float* __restrict__ bias,
    unsigned short* __restrict__ out) {
  size_t i = ((size_t)blockIdx.x * 256 + threadIdx.x) * 8;
  const float4* p = (const float4*)(part + i);
  const size_t s4 = 2097152 / 4;  // float4 stride per split
  float4 a0 = p[0], a1 = p[1];
#pragma unroll
  for (int s = 1; s < NS; s++) {
    float4 b0 = p[s * s4], b1 = p[s * s4 + 1];
    a0.x += b0.x; a0.y += b0.y; a0.z += b0.z; a0.w += b0.w;
    a1.x += b1.x; a1.y += b1.y; a1.z += b1.z; a1.w += b1.w;
  }
  int col = (int)(i & 255);
  unsigned short t8[8] = {
      f2bf(a0.x + bias[col + 0]), f2bf(a0.y + bias[col + 1]),
      f2bf(a0.z + bias[col + 2]), f2bf(a0.w + bias[col + 3]),
      f2bf(a1.x + bias[col + 4]), f2bf(a1.y + bias[col + 5]),
      f2bf(a1.z + bias[col + 6]), f2bf(a1.w + bias[col + 7])};
  *(uint4*)(out + i) = *(const uint4*)t8;
}

// ---------------------------------------------------------------------------
// Embed GEMM, fused im2col, counted-vmcnt pipeline, split-K x4:
//   Cpart[z][8192][256] f32 = x-as-A[8192, z*1024 .. +1024] * wE^T
// Per k-step (32 total): {ds_read frags; issue x(t+2)->regs + gll B(t+2)->
// LDS ring; MFMA; cvt x(t+1)->As[nxt]; asm vmcnt(6)+lgkmcnt(0)+s_barrier}.
// vmcnt(6) = this step's own 6 VMEM ops stay in flight; everything older
// (tile t+1's loads) is retired. A double-buffered, B quad-buffered.
__global__ __launch_bounds__(256) void gemm_embed_kernel(
    const float* __restrict__ x, const unsigned short* __restrict__ Bw,
    float* __restrict__ Cpart) {
  __shared__ unsigned short As[2 * 4096];  // 16 KB
  __shared__ unsigned short Bs[4 * 4096];  // 32 KB
  int tid = threadIdx.x;
  int lane = tid & 63, wave = tid >> 6;

  int L = blockIdx.x;              // 0..511
  int xcd = L & 7, j = L >> 3;     // j 0..63
  int pair = xcd * 32 + (j >> 1);  // 0..255 (bijective)
  int n0 = (j & 1) * 128;
  int z = pair & 3, y = pair >> 2;
  int m0 = y * 128;
  int wm = (wave & 1) * 64, wn = (wave >> 1) * 64;
  int fr = lane & 15, fh = lane >> 4;

  f32x4 acc[4][4];
#pragma unroll
  for (int i = 0; i < 4; i++)
#pragma unroll
    for (int jj = 0; jj < 4; jj++) acc[i][jj] = (f32x4){0.f, 0.f, 0.f, 0.f};

  int f0 = tid, f1 = tid + 256;
  // B staging (bf16 weights [256][4096]) via global_load_lds, quad ring
  const unsigned short* Bg0 =
      Bw + (size_t)(n0 + (f0 >> 2)) * 4096 + z * 1024 + (f0 & 3) * 8;
  const unsigned short* Bg1 =
      Bw + (size_t)(n0 + (f1 >> 2)) * 4096 + z * 1024 + (f1 & 3) * 8;
  unsigned short* Bl0 = Bs + f0 * 8;
  unsigned short* Bl1 = Bs + f1 * 8;

  // A staging from x: chunk f -> row r=f>>2, ch=f&3;
  // k = z*1024 + t*32 + ch*8 -> c = z*64 + 2t + (ch>>1), p0 = (2ch)&3
  const float4* x4 = (const float4*)x;
  int r0 = f0 >> 2, ch0 = f0 & 3;
  int m_0 = m0 + r0, b_0 = m_0 >> 10, hp0 = (m_0 >> 5) & 31, wp0 = m_0 & 31;
  int c_0 = z * 64 + (ch0 >> 1), p_0 = (2 * ch0) & 3;
  const float4* xp0 =
      x4 + (size_t)((b_0 * 256 + c_0) * 128 + hp0 * 4 + p_0) * 32 + wp0;
  int r1 = f1 >> 2, ch1 = f1 & 3;
  int m_1 = m0 + r1, b_1 = m_1 >> 10, hp1 = (m_1 >> 5) & 31, wp1 = m_1 & 31;
  int c_1 = z * 64 + (ch1 >> 1), p_1 = (2 * ch1) & 3;
  const float4* xp1 =
      x4 + (size_t)((b_1 * 256 + c_1) * 128 + hp1 * 4 + p_1) * 32 + wp1;
  unsigned short* Al0 = As + f0 * 8;
  unsigned short* Al1 = As + f1 * 8;

  float4 aP[4], aQ[4];  // two named tile sets (x data, f32)

  // ---- prologue: tiles 0 and 1 in flight ----
  aP[0] = xp0[0]; aP[1] = xp0[32]; aP[2] = xp1[0]; aP[3] = xp1[32];
  async_ld16(Bg0, Bl0);
  async_ld16(Bg1, Bl1);
  asm volatile("" ::: "memory");  // fence: tile-0 issue group before tile-1
  aQ[0] = xp0[8192]; aQ[1] = xp0[8224]; aQ[2] = xp1[8192]; aQ[3] = xp1[8224];
  async_ld16(Bg0 + 32, Bl0 + 4096);
  async_ld16(Bg1 + 32, Bl1 + 4096);
  cvt8_store(Al0, aP[0], aP[1]);  // compiler inserts counted vmcnt for x(0)
  cvt8_store(Al1, aP[2], aP[3]);
  // retire tile-0 ops (B(0)); keep tile-1's 6 in flight; publish As[0]
  asm volatile("s_waitcnt vmcnt(6) lgkmcnt(0)\n\ts_barrier" ::: "memory");

  auto half = [&](int t, float4 (&aCur)[4], float4 (&aNext)[4]) {
    const unsigned short* Asc = As + ((t & 1) << 12);
    const unsigned short* Bsc = Bs + ((t & 3) << 12);
    bf16x8 af[4], bfr[4];
#pragma unroll
    for (int tt = 0; tt < 4; tt++) {
      af[tt] = *(const bf16x8*)(Asc + (wm + tt * 16 + fr) * 32 + fh * 8);
      bfr[tt] = *(const bf16x8*)(Bsc + (wn + tt * 16 + fr) * 32 + fh * 8);
    }
    int tc = (t + 2 > 31) ? 31 : t + 2;  // clamp keeps VMEM count uniform
    size_t ax = (size_t)tc * 8192;
    aCur[0] = xp0[ax]; aCur[1] = xp0[ax + 32];
    aCur[2] = xp1[ax]; aCur[3] = xp1[ax + 32];
    async_ld16(Bg0 + (tc << 5), Bl0 + ((tc & 3) << 12));
    async_ld16(Bg1 + (tc << 5), Bl1 + ((tc & 3) << 12));
    __builtin_amdgcn_s_setprio(1);
#pragma unroll
    for (int mt = 0; mt < 4; mt++)
#pragma unroll
      for (int nt = 0; nt < 4; nt++)
        acc[mt][nt] = __builtin_amdgcn_mfma_f32_16x16x32_bf16(
            af[mt], bfr[nt], acc[mt][nt], 0, 0, 0);
    __builtin_amdgcn_s_setprio(0);
    // stage tile t+1 (loaded one full step ago) into the A buffer freed above
    cvt8_store(Al0 + (((t + 1) & 1) << 12), aNext[0], aNext[1]);
    cvt8_store(Al1 + (((t + 1) & 1) << 12), aNext[2], aNext[3]);
    // counted drain: retire tile-(t+1) loads, keep this step's 6 in flight
    asm volatile("s_waitcnt vmcnt(6) lgkmcnt(0)\n\ts_barrier" ::: "memory");
  };

  for (int it = 0; it < 16; it++) {
    half(2 * it, aP, aQ);
    half(2 * it + 1, aQ, aP);
  }

  // epilogue: f32 partials (C/D layout col = lane&15, row = (lane>>4)*4 + r)
  float* Cp = Cpart + (size_t)z * 2097152;
#pragma unroll
  for (int mt = 0; mt < 4; mt++) {
    int row0 = m0 + wm + mt * 16 + fh * 4;
#pragma unroll
    for (int nt = 0; nt < 4; nt++) {
      int col = n0 + wn + nt * 16 + fr;
#pragma unroll
      for (int r = 0; r < 4; r++)
        Cp[(size_t)(row0 + r) * 256 + col] = acc[mt][nt][r];
    }
  }
}

// ---------------------------------------------------------------------------
// bf16 MFMA GEMM: C[M,N] = A[M,K] * B^T (B given [N,K] bf16) + bias.
// CMODE: 1 = bf16 C, 2 = fused col2im into y[8,256,128,128] f32,
//        3 = fused QKV split, 4 = split-K f32 partials.
template <int CMODE>
__global__ __launch_bounds__(256) void gemm_mfma_kernel(
    const unsigned short* __restrict__ A, const unsigned short* __restrict__ B,
    const float* __restrict__ bias, void* __restrict__ Cv,
    int M, int N, int K, int lda, int ldb, int ldc) {
  __shared__ unsigned short As[2 * 128 * 32];
  __shared__ unsigned short Bs[2 * 128 * 32];
  int tid = threadIdx.x;
  int lane = tid & 63;
  int wave = tid >> 6;
  int m0 = blockIdx.y * 128, n0 = blockIdx.x * 128;
  int wm = (wave & 1) * 64, wn = (wave >> 1) * 64;

  if (CMODE == 4) {
    int s = blockIdx.z;
    A += (size_t)s * K;
    B += (size_t)s * K;
    Cv = (void*)((float*)Cv + (size_t)s * M * N);
  }

  f32x4 acc[4][4];
#pragma unroll
  for (int i = 0; i < 4; i++)
#pragma unroll
    for (int j = 0; j < 4; j++) acc[i][j] = (f32x4){0.f, 0.f, 0.f, 0.f};

  int f0 = tid, f1 = tid + 256;
  const unsigned short* Ag0 = A + (size_t)(m0 + (f0 >> 2)) * lda + (f0 & 3) * 8;
  const unsigned short* Ag1 = A + (size_t)(m0 + (f1 >> 2)) * lda + (f1 & 3) * 8;
  const unsigned short* Bg0 = B + (size_t)(n0 + (f0 >> 2)) * ldb + (f0 & 3) * 8;
  const unsigned short* Bg1 = B + (size_t)(n0 + (f1 >> 2)) * ldb + (f1 & 3) * 8;
  unsigned short* Al0 = As + f0 * 8;
  unsigned short* Al1 = As + f1 * 8;
  unsigned short* Bl0 = Bs + f0 * 8;
  unsigned short* Bl1 = Bs + f1 * 8;

  int fr = lane & 15;
  int fh = lane >> 4;

  int ntiles = K >> 5;
  async_ld16(Ag0, Al0);
  async_ld16(Ag1, Al1);
  async_ld16(Bg0, Bl0);
  async_ld16(Bg1, Bl1);
  __syncthreads();

  for (int t = 0; t < ntiles; t++) {
    int cur = (t & 1) << 12;
    int nxt = cur ^ 4096;
    if (t + 1 < ntiles) {
      int kn = (t + 1) << 5;
      async_ld16(Ag0 + kn, Al0 + nxt);
      async_ld16(Ag1 + kn, Al1 + nxt);
      async_ld16(Bg0 + kn, Bl0 + nxt);
      async_ld16(Bg1 + kn, Bl1 + nxt);
    }
    const unsigned short* Asc = As + cur;
    const unsigned short* Bsc = Bs + cur;
    bf16x8 af[4], bfr[4];
#pragma unroll
    for (int tt = 0; tt < 4; tt++) {
      af[tt] = *(const bf16x8*)(Asc + (wm + tt * 16 + fr) * 32 + fh * 8);
      bfr[tt] = *(const bf16x8*)(Bsc + (wn + tt * 16 + fr) * 32 + fh * 8);
    }
#pragma unroll
    for (int mt = 0; mt < 4; mt++)
#pragma unroll
      for (int nt = 0; nt < 4; nt++)
        acc[mt][nt] = __builtin_amdgcn_mfma_f32_16x16x32_bf16(
            af[mt], bfr[nt], acc[mt][nt], 0, 0, 0);
    __syncthreads();
  }

#pragma unroll
  for (int mt = 0; mt < 4; mt++) {
    int row0 = m0 + wm + mt * 16 + fh * 4;
    if (CMODE == 2) {
      int b = row0 >> 10, hp = (row0 >> 5) & 31, wp = row0 & 31;
      size_t rowoff0 = (size_t)b * 4194304 + hp * 512 + wp * 4;
      float* y = (float*)Cv;
#pragma unroll
      for (int nt = 0; nt < 4; nt++) {
        int col = n0 + wn + nt * 16 + fr;
        int o = col >> 4, p = (col >> 2) & 3, q = col & 3;
        size_t coloff = (size_t)o * 16384 + p * 128 + q;
        float bv = bias[o];
#pragma unroll
        for (int r = 0; r < 4; r++)
          y[rowoff0 + r * 4 + coloff] = acc[mt][nt][r] + bv;
      }
    } else if (CMODE == 3) {
      unsigned short* base = (unsigned short*)Cv;
#pragma unroll
      for (int nt = 0; nt < 4; nt++) {
        int col = n0 + wn + nt * 16 + fr;
        int which = col >> 8, hh = (col >> 5) & 7, d = col & 31;
        float bv = bias[col];
#pragma unroll
        for (int r = 0; r < 4; r++) {
          int row = row0 + r;
          int bb = row >> 10, nn = row & 1023;
          int bh = bb * 8 + hh;
          float v = acc[mt][nt][r] + bv;
          if (which == 0) v *= 0.17677669529663687f;  // 1/sqrt(32)
          size_t addr;
          if (which < 2)
            addr = (size_t)which * 2097152 + ((size_t)bh * 1024 + nn) * 32 + d;
          else
            addr = (size_t)2 * 2097152 + (size_t)bh * 32768 + (size_t)d * 1024 + nn;
          base[addr] = f2bf(v);
        }
      }
    } else if (CMODE == 4) {
      float* Cp = (float*)Cv;
#pragma unroll
      for (int nt = 0; nt < 4; nt++) {
        int col = n0 + wn + nt * 16 + fr;
#pragma unroll
        for (int r = 0; r < 4; r++)
          Cp[(size_t)(row0 + r) * ldc + col] = acc[mt][nt][r];
      }
    } else {
#pragma unroll
      for (int nt = 0; nt < 4; nt++) {
        int col = n0 + wn + nt * 16 + fr;
        float bv = bias ? bias[col] : 0.f;
        unsigned short* C = (unsigned short*)Cv;
#pragma unroll
        for (int r = 0; r < 4; r++)
          C[(size_t)(row0 + r) * ldc + col] = f2bf(acc[mt][nt][r] + bv);
      }
    }
  }
}

// ---------------------------------------------------------------------------
// MFMA flash attention — barrier-free, rolled 8x2 pipelined loop (round 7).
__global__ __launch_bounds__(512) void attn_mfma_kernel(
    const unsigned short* __restrict__ Qb, const unsigned short* __restrict__ Kb,
    const unsigned short* __restrict__ Vtb,
    const float* __restrict__ tableT,
    unsigned short* __restrict__ out) {
  __shared__ float th[3972];                 // per-head RPE table column
  __shared__ unsigned short Ps[2][8][1088];  // [half][wave][16*68] P scratch

  int tid = threadIdx.x;
  int lane = tid & 63, w = tid >> 6;
  int n = lane & 15, g = lane >> 4;
  int blk = blockIdx.x;
  int h = blk & 7, b = (blk >> 3) & 7, qt = blk >> 6;
  int bh = b * 8 + h;
  int q0 = qt * 128;

  const unsigned short* Qg = Qb + ((size_t)bh * 1024 + q0) * 32;
  const unsigned short* Kg = Kb + (size_t)bh * 1024 * 32;
  const unsigned short* Vg = Vtb + (size_t)bh * 32 * 1024;
  const float* tg = tableT + (size_t)h * 4096;

  for (int i = tid; i < 3969; i += 512) th[i] = tg[i];
  bf16x8 qf = *(const bf16x8*)(Qg + (size_t)(w * 16 + n) * 32 + g * 8);
  __syncthreads();  // table ready — the only barrier

  f32x4 oacc[2];
  oacc[0] = (f32x4){0.f, 0.f, 0.f, 0.f};
  oacc[1] = (f32x4){0.f, 0.f, 0.f, 0.f};
  float m_run = -1e30f, l_run = 0.f;  // l_run g-partial, reduced at end

  int q = q0 + w * 16 + n;
  int tbase = (q >> 5) * 63 + (q & 31) + 1984;  // + (31*63+31)

  unsigned short* PwA = &Ps[0][w][0];
  unsigned short* PwB = &Ps[1][w][0];

  bf16x8 kfA[4], kfB[4];
#pragma unroll
  for (int mt = 0; mt < 4; mt++)
    kfA[mt] = *(const bf16x8*)(Kg + (size_t)(mt * 16 + n) * 32 + g * 8);

  auto half_step = [&](const bf16x8 (&kf)[4], int k0, unsigned short* Pw) {
    bf16x8 vf[4];
#pragma unroll
    for (int i = 0; i < 4; i++)
      vf[i] = *(const bf16x8*)(Vg + (size_t)((i & 1) * 16 + n) * 1024 + k0 +
                               (i >> 1) * 32 + g * 8);

    f32x4 s[4];
    __builtin_amdgcn_s_setprio(1);
#pragma unroll
    for (int mt = 0; mt < 4; mt++)
      s[mt] = __builtin_amdgcn_mfma_f32_16x16x32_bf16(
          kf[mt], qf, (f32x4){0.f, 0.f, 0.f, 0.f}, 0, 0, 0);
    __builtin_amdgcn_s_setprio(0);

#pragma unroll
    for (int mt = 0; mt < 4; mt++) {
      int kb = k0 + mt * 16 + g * 4;
      int ib = tbase - (kb >> 5) * 63 - (kb & 31);
      s[mt][0] += th[ib];
      s[mt][1] += th[ib - 1];
      s[mt][2] += th[ib - 2];
      s[mt][3] += th[ib - 3];
    }

    float mx = -1e30f;
#pragma unroll
    for (int mt = 0; mt < 4; mt++)
#pragma unroll
      for (int r = 0; r < 4; r++) mx = fmaxf(mx, s[mt][r]);
    mx = fmaxf(mx, __shfl_xor(mx, 16, 64));
    mx = fmaxf(mx, __shfl_xor(mx, 32, 64));
    float m_new = fmaxf(m_run, mx);
    float alpha = __expf(m_run - m_new);
    m_run = m_new;

    float ls = 0.f;
#pragma unroll
    for (int mt = 0; mt < 4; mt++) {
#pragma unroll
      for (int r = 0; r < 4; r++) {
        float p = __expf(s[mt][r] - m_new);
        s[mt][r] = p;
        ls += p;
      }
      u16x4 pk = {f2bf(s[mt][0]), f2bf(s[mt][1]), f2bf(s[mt][2]),
                  f2bf(s[mt][3])};
      *(u16x4*)(Pw + n * 68 + mt * 16 + g * 4) = pk;
    }
    l_run = l_run * alpha + ls;

#pragma unroll
    for (int dt = 0; dt < 2; dt++)
#pragma unroll
      for (int r = 0; r < 4; r++) oacc[dt][r] *= alpha;
    __builtin_amdgcn_s_setprio(1);
#pragma unroll
    for (int kt = 0; kt < 2; kt++) {
      bf16x8 pf = *(const bf16x8*)(Pw + n * 68 + kt * 32 + g * 8);
      oacc[0] = __builtin_amdgcn_mfma_f32_16x16x32_bf16(vf[kt * 2 + 0], pf,
                                                        oacc[0], 0, 0, 0);
      oacc[1] = __builtin_amdgcn_mfma_f32_16x16x32_bf16(vf[kt * 2 + 1], pf,
                                                        oacc[1], 0, 0, 0);
    }
    __builtin_amdgcn_s_setprio(0);
  };

  for (int tt = 0; tt < 8; tt++) {
    int k0 = tt * 128;
#pragma unroll
    for (int mt = 0; mt < 4; mt++)
      kfB[mt] = *(const bf16x8*)(Kg + (size_t)(k0 + 64 + mt * 16 + n) * 32 +
                                 g * 8);
    half_step(kfA, k0, PwA);
    if (tt < 7) {
#pragma unroll
      for (int mt = 0; mt < 4; mt++)
        kfA[mt] = *(const bf16x8*)(Kg + (size_t)(k0 + 128 + mt * 16 + n) * 32 +
                                   g * 8);
    }
    half_step(kfB, k0 + 64, PwB);
  }

  float l = l_run;
  l += __shfl_xor(l, 16, 64);
  l += __shfl_xor(l, 32, 64);
  float invl = 1.f / l;
  unsigned short* ob = out + ((size_t)(b * 1024 + q) * 256) + h * 32;
#pragma unroll
  for (int dt = 0; dt < 2; dt++) {
    u16x4 o4 = {f2bf(oacc[dt][0] * invl), f2bf(oacc[dt][1] * invl),
                f2bf(oacc[dt][2] * invl), f2bf(oacc[dt][3] * invl)};
    *(u16x4*)(ob + dt * 16 + g * 4) = o4;
  }
}

// ---------------------------------------------------------------------------
extern "C" void kernel_launch(void* const* d_in, const int* in_sizes, int n_in,
                              void* d_out, int out_size, void* d_ws, size_t ws_size,
                              hipStream_t stream) {
  const float* x         = (const float*)d_in[0];
  const float* w_embed   = (const float*)d_in[1];
  const float* b_embed   = (const float*)d_in[2];
  const float* cpb_w1    = (const float*)d_in[3];
  const float* cpb_b1    = (const float*)d_in[4];
  const float* cpb_w2    = (const float*)d_in[5];
  const float* w_qkv     = (const float*)d_in[6];
  const float* b_qkv     = (const float*)d_in[7];
  const float* w_proj    = (const float*)d_in[8];
  const float* b_proj    = (const float*)d_in[9];
  const float* w_unembed = (const float*)d_in[10];
  const float* b_unembed = (const float*)d_in[11];
  float* out = (float*)d_out;

  // workspace layout
  char* w = (char*)d_ws;
  float*          ProjP = (float*)w;          w += (size_t)8388608 * 4;      // 32 MB (proj partials)
  unsigned short* tok   = (unsigned short*)w; w += (size_t)8192 * 256 * 2;   //  4 MB
  unsigned short* wE    = (unsigned short*)w; w += (size_t)1048576 * 2;      //  2 MB
  unsigned short* wQ    = (unsigned short*)w; w += (size_t)196608 * 2;       // 384 KB
  unsigned short* wP    = (unsigned short*)w; w += (size_t)65536 * 2;        // 128 KB
  unsigned short* wUt   = (unsigned short*)w; w += (size_t)1048576 * 2;      //  2 MB
  float*          tableT= (float*)w;          w += (size_t)32768 * 4;        // 128 KB
  float*          PART  = (float*)w;          w += (size_t)4 * 2097152 * 4;  // 32 MB (embed partials x4)

  // live-range aliases inside PART (embed partials dead once reduced):
  unsigned short* qkvB  = (unsigned short*)PART;                     // 12 MB
  unsigned short* attno = (unsigned short*)((char*)PART + 12582912); //  4 MB
  unsigned short* z2    = (unsigned short*)((char*)PART + 16777216); //  4 MB
  unsigned short* Qb  = qkvB;
  unsigned short* Kb  = qkvB + 2097152;
  unsigned short* Vtb = qkvB + 2 * 2097152;

  // ---- prep (weights, RPE table) ----
  cvt_bf16_kernel<<<512, 256, 0, stream>>>(w_embed, wE, 131072);
  cvt_bf16_kernel<<<96, 256, 0, stream>>>(w_qkv, wQ, 24576);
  cvt_bf16_kernel<<<32, 256, 0, stream>>>(w_proj, wP, 8192);
  transpose_cvt_kernel<<<dim3(128, 8), 256, 0, stream>>>(w_unembed, wUt);
  rpe_table_kernel<<<16, 256, 0, stream>>>(cpb_w1, cpb_b1, cpb_w2, tableT);

  // ---- embed: counted-vmcnt fused-im2col split-K x4 -> reduce -> tok ----
  gemm_embed_kernel<<<512, 256, 0, stream>>>(x, wE, PART);
  splitk_reduce_kernel<4><<<1024, 256, 0, stream>>>(PART, b_embed, tok);

  // ---- qkv + fused split/scale/transpose into Qb/Kb/Vtb ----
  gemm_mfma_kernel<3><<<dim3(6, 64), 256, 0, stream>>>(
      tok, wQ, b_qkv, qkvB, 8192, 768, 256, 256, 256, 0);

  // ---- attention (barrier-free, rolled 8x2) ----
  attn_mfma_kernel<<<512, 512, 0, stream>>>(Qb, Kb, Vtb, tableT, attno);

  // ---- proj: split-K x4 -> reduce -> z2 ----
  gemm_mfma_kernel<4><<<dim3(2, 64, 4), 256, 0, stream>>>(
      attno, wP, nullptr, ProjP, 8192, 256, 64, 256, 256, 256);
  splitk_reduce_kernel<4><<<1024, 256, 0, stream>>>(ProjP, b_proj, z2);

  // ---- unembed + fused col2im ----
  gemm_mfma_kernel<2><<<dim3(32, 64), 256, 0, stream>>>(
      z2, wUt, b_unembed, out, 8192, 4096, 256, 256, 256, 0);
}